// Round 2
// baseline (32.585 us; speedup 1.0000x reference)
//
#include <hip/hip_runtime.h>

#define N_LAYERS 512
#define DEL_Z (0.9f / 512.0f)

// Stage 1: precompute per-layer wave-uniform constants into d_ws (SoA, 5 x 512 f32):
//   c0 = 1 + g,            g = 1 - b2/b1
//   c1 = g*inv1 - DEL_Z*inv2
//   i1 = inv1 = 1/(PiT*(1-z)),  inv2 = inv1/(1-z)
//   c3 = inv1^2 - inv2/PiT + 1/b1^2
//   c4 = z^2 / b1                     (MU^2 == 1; the 1/omega^2 factor applied per-thread)
__global__ __launch_bounds__(256) void metric_setup_kernel(
    const float* __restrict__ PiT_p, const float* __restrict__ B,
    float* __restrict__ C)
{
    const int l = blockIdx.x * 256 + threadIdx.x;
    if (l >= N_LAYERS) return;
    const float PiT  = PiT_p[0];
    const float z    = DEL_Z * (float)l;      // Z_INI == 0
    const float b1   = B[l];
    const float b2   = B[l + 1];
    const float omz  = 1.0f - z;
    const float inv1 = 1.0f / (PiT * omz);
    const float inv2 = inv1 / omz;
    const float g    = 1.0f - b2 / b1;
    C[0 * N_LAYERS + l] = 1.0f + g;                                    // c0
    C[1 * N_LAYERS + l] = g * inv1 - DEL_Z * inv2;                     // c1
    C[2 * N_LAYERS + l] = inv1;                                        // i1
    C[3 * N_LAYERS + l] = inv1 * inv1 - inv2 / PiT + 1.0f / (b1 * b1); // c3
    C[4 * N_LAYERS + l] = z * z / b1;                                  // c4
}

// Stage 2: per-element 512-step scan. Constants read with a loop-uniform index
// from read-only global memory -> expected to lower to s_load (SMEM, scalar
// cache), freeing the VALU/DS issue ports entirely for the 10 FMA-class ops.
// Per step (exact algebra of the reference):
//   Rn = c0*Re + c1 + 2*DEL_Z*om*Im*(Re + i1)
//   Im = c0*Im + DEL_Z*om*(Im^2 - (Rn+i1)^2 + c3 - c4/om^2)
__global__ __launch_bounds__(256) void metric_scan_kernel(
    const float* __restrict__ Re_s, const float* __restrict__ Im_s,
    const float* __restrict__ omega, const float* __restrict__ C,
    float* __restrict__ out, int n)
{
    const float* __restrict__ C0 = C + 0 * N_LAYERS;
    const float* __restrict__ C1 = C + 1 * N_LAYERS;
    const float* __restrict__ CI = C + 2 * N_LAYERS;
    const float* __restrict__ C3 = C + 3 * N_LAYERS;
    const float* __restrict__ C4 = C + 4 * N_LAYERS;

    const int i = blockIdx.x * 256 + threadIdx.x;
    float Re = Re_s[i];
    float Im = Im_s[i];
    const float om    = omega[i];
    const float dzom  = DEL_Z * om;
    const float dz2om = 2.0f * dzom;
    const float iom   = 1.0f / om;
    const float iom2  = iom * iom;

    #pragma unroll 8
    for (int l = 0; l < N_LAYERS; ++l) {
        const float c0 = C0[l];
        const float c1 = C1[l];
        const float i1 = CI[l];
        const float c3 = C3[l];
        const float c4 = C4[l];
        const float t  = Re + i1;                 // Re + inv1
        const float a  = fmaf(c0, Re, c1);        // c0*Re + c1
        const float m  = dz2om * Im;
        const float Rn = fmaf(m, t, a);
        const float u  = Rn + i1;                 // Rn + inv1
        float s = fmaf(Im, Im, c3);               // Im^2 + c3          (off-chain)
        s = fmaf(-c4, iom2, s);                   //  - c4/om^2         (off-chain)
        const float b = c0 * Im;                  //                    (off-chain)
        s = fmaf(-u, u, s);                       //  - u^2             (on-chain, last)
        Im = fmaf(dzom, s, b);
        Re = Rn;
    }

    out[i]     = Re;
    out[n + i] = Im;
}

extern "C" void kernel_launch(void* const* d_in, const int* in_sizes, int n_in,
                              void* d_out, int out_size, void* d_ws, size_t ws_size,
                              hipStream_t stream)
{
    const float* Re_s  = (const float*)d_in[0];
    const float* Im_s  = (const float*)d_in[1];
    const float* omega = (const float*)d_in[2];
    const float* PiT   = (const float*)d_in[3];
    const float* B     = (const float*)d_in[4];
    float* out = (float*)d_out;
    float* C   = (float*)d_ws;                    // 5*512*4 B = 10 KB scratch
    const int n = in_sizes[0];                    // 131072

    metric_setup_kernel<<<2, 256, 0, stream>>>(PiT, B, C);
    metric_scan_kernel<<<n / 256, 256, 0, stream>>>(Re_s, Im_s, omega, C, out, n);
}